// Round 9
// baseline (943.584 us; speedup 1.0000x reference)
//
#include <hip/hip_runtime.h>
#include <math.h>

#define EPSV 1e-5f

typedef __attribute__((ext_vector_type(8))) short short8;
typedef __attribute__((ext_vector_type(4))) float f32x4;

__device__ inline unsigned short f2bf(float x) {
  unsigned int u = __float_as_uint(x);
  return (unsigned short)((u + 0x7FFFu + ((u >> 16) & 1u)) >> 16);
}
__device__ inline float bf2f(unsigned short v) {
  return __uint_as_float(((unsigned int)v) << 16);
}

// ============================================================================
// Pack all conv weights fp32 [Cout][Cin][3][3] -> bf16 [9][128][Cin], one launch
// ============================================================================
__global__ void packall_k(const float* __restrict__ W_up, const float* __restrict__ W_r1,
                          const float* __restrict__ W_r2, const float* __restrict__ W_ll,
                          const float* __restrict__ W_hi, unsigned short* __restrict__ p_up,
                          unsigned short* __restrict__ p_r1, unsigned short* __restrict__ p_r2,
                          unsigned short* __restrict__ p_dt) {
  int idx = blockIdx.x * 256 + threadIdx.x;
  const float* src; unsigned short* dst; int Cin, co_off, local;
  if (idx < 294912)       { src = W_up; dst = p_up; Cin = 256; co_off = 0;  local = idx; }
  else if (idx < 442368)  { src = W_r1; dst = p_r1; Cin = 128; co_off = 0;  local = idx - 294912; }
  else if (idx < 589824)  { src = W_r2; dst = p_r2; Cin = 128; co_off = 0;  local = idx - 442368; }
  else if (idx < 626688)  { src = W_ll; dst = p_dt; Cin = 128; co_off = 0;  local = idx - 589824; }
  else if (idx < 737280)  { src = W_hi; dst = p_dt; Cin = 128; co_off = 32; local = idx - 626688; }
  else return;
  int kk = local % 9;
  int ci = (local / 9) % Cin;
  int co = local / (9 * Cin);
  dst[((long)kk * 128 + co_off + co) * Cin + ci] = f2bf(src[local]);
}

// ============================================================================
// Tiled NCHW fp32 -> NHWC bf16 transpose/convert (+optional NCHW bf16 copy).
// ============================================================================
__global__ void t_nhwc_k(const float* __restrict__ in, unsigned short* __restrict__ out,
                         unsigned short* __restrict__ out_nchw, int C, int HW) {
  __shared__ unsigned short lds[64][34];
  int b = blockIdx.z;
  int c0 = blockIdx.y << 5;
  int hw0 = blockIdx.x << 6;
  int t = threadIdx.x;
  int c = t >> 3, j0 = (t & 7) << 3;
  long ibase = ((long)b * C + c0 + c) * HW + hw0 + j0;
  const float* p = in + ibase;
  int4 nv; unsigned short* ns = (unsigned short*)&nv;
#pragma unroll
  for (int j = 0; j < 8; j++) {
    unsigned short v = f2bf(p[j]);
    lds[j0 + j][c] = v;
    ns[j] = v;
  }
  if (out_nchw) *(int4*)(out_nchw + ibase) = nv;
  __syncthreads();
  int hw = t >> 2, k = (t & 3) << 3;
  unsigned short* q = out + ((long)(b * HW + hw0 + hw)) * C + c0 + k;
  int4 val;
  unsigned short* vs = (unsigned short*)&val;
#pragma unroll
  for (int i = 0; i < 8; i++) vs[i] = lds[hw][k + i];
  *(int4*)q = val;
}

// ============================================================================
// GN-apply fused with NHWC bf16 transpose (att_out -> conv r1 input)
// ============================================================================
__global__ void gnout_nhwc_k(const float* __restrict__ in, const float* __restrict__ sums,
                             const float* __restrict__ gamma, const float* __restrict__ beta,
                             unsigned short* __restrict__ out) {
  __shared__ unsigned short lds[64][34];
  int b = blockIdx.z;
  int c0 = blockIdx.y << 5;
  int hw0 = blockIdx.x << 6;
  int t = threadIdx.x;
  int c = t >> 3, j0 = (t & 7) << 3;
  int ch = c0 + c;
  int sidx = b * 8 + (ch >> 4);
  const float ic = 1.f / 262144.f;
  float m = sums[2 * sidx] * ic;
  float r = rsqrtf(fmaxf(sums[2 * sidx + 1] * ic - m * m, 0.f) + EPSV);
  float ga = gamma[ch] * r, be = beta[ch] - m * r * gamma[ch];
  const float* p = in + (((long)(b * 128 + ch)) << 14) + hw0 + j0;
#pragma unroll
  for (int j = 0; j < 8; j++) lds[j0 + j][c] = f2bf(p[j] * ga + be);
  __syncthreads();
  int hw = t >> 2, k = (t & 3) << 3;
  unsigned short* q = out + ((long)(b * 16384 + hw0 + hw)) * 128 + c0 + k;
  int4 val;
  unsigned short* vs = (unsigned short*)&val;
#pragma unroll
  for (int i = 0; i < 8; i++) vs[i] = lds[hw][k + i];
  *(int4*)q = val;
}

// BN+relu fused with NHWC bf16 transpose (r1 -> conv r2 input)
__global__ void bnrelu_nhwc_k(const float* __restrict__ in, const float* __restrict__ sums,
                              const float* __restrict__ gamma, const float* __restrict__ beta,
                              unsigned short* __restrict__ out) {
  __shared__ unsigned short lds[64][34];
  int b = blockIdx.z;
  int c0 = blockIdx.y << 5;
  int hw0 = blockIdx.x << 6;
  int t = threadIdx.x;
  int c = t >> 3, j0 = (t & 7) << 3;
  int ch = c0 + c;
  const float ic = 1.f / 65536.f;
  float m = sums[2 * ch] * ic;
  float r = rsqrtf(fmaxf(sums[2 * ch + 1] * ic - m * m, 0.f) + EPSV);
  float ga = gamma[ch] * r, be = beta[ch] - m * r * gamma[ch];
  const float* p = in + (((long)(b * 128 + ch)) << 14) + hw0 + j0;
#pragma unroll
  for (int j = 0; j < 8; j++) lds[j0 + j][c] = f2bf(fmaxf(p[j] * ga + be, 0.f));
  __syncthreads();
  int hw = t >> 2, k = (t & 3) << 3;
  unsigned short* q = out + ((long)(b * 16384 + hw0 + hw)) * 128 + c0 + k;
  int4 val;
  unsigned short* vs = (unsigned short*)&val;
#pragma unroll
  for (int i = 0; i < 8; i++) vs[i] = lds[hw][k + i];
  *(int4*)q = val;
}

// ============================================================================
// TILED bilinear resize (align-corners) fp32 NCHW 64x64 -> bf16 NHWC 128x128.
// grid (128 ho, C/32, 4), block 256; each thread covers TWO wo positions.
// ============================================================================
__global__ __launch_bounds__(256) void resize_t_k(const float* __restrict__ in,
                                                  unsigned short* __restrict__ out,
                                                  int C, float s) {
  __shared__ float rows[2][32][68];
  int ho = blockIdx.x, cb = blockIdx.y, b = blockIdx.z;
  int t = threadIdx.x;
  float ys = ho * s;
  int y0 = (int)ys; float wy = ys - y0;
  int y1 = min(y0 + 1, 63);
  for (int i = t; i < 1024; i += 256) {
    int r = i >> 9, c = (i >> 4) & 31, seg = i & 15;
    const float* p = in + (((long)(b * C + cb * 32 + c)) << 12) + ((r ? y1 : y0) << 6) + (seg << 2);
    *(float4*)&rows[r][c][seg << 2] = *(const float4*)p;
  }
  __syncthreads();
  int cs = t & 3;
#pragma unroll
  for (int half = 0; half < 2; half++) {
    int wo = (t >> 2) + half * 64;
    float xs = wo * s;
    int x0 = (int)xs; float wx = xs - x0;
    int x1 = min(x0 + 1, 63);
    int4 val; unsigned short* vs = (unsigned short*)&val;
#pragma unroll
    for (int j = 0; j < 8; j++) {
      int c = cs * 8 + j;
      float v00 = rows[0][c][x0], v01 = rows[0][c][x1];
      float v10 = rows[1][c][x0], v11 = rows[1][c][x1];
      float r0 = v00 + (v01 - v00) * wx;
      float r1 = v10 + (v11 - v10) * wx;
      vs[j] = f2bf(r0 + (r1 - r0) * wy);
    }
    *(int4*)(out + ((long)((b * 128 + ho) * 128 + wo)) * C + cb * 32 + cs * 8) = val;
  }
}

// Bilinear resize fp32 NCHW -> bf16 NCHW (skip_global feats copy), 8 wo/thread
__global__ void resize_nchwbf_k(const float* __restrict__ in, unsigned short* __restrict__ out,
                                float s) {
  long idx = (long)blockIdx.x * 256 + threadIdx.x;  // 1048576 total
  int seg = (int)(idx & 15); long t2 = idx >> 4;
  int ho = (int)(t2 & 127); t2 >>= 7;
  int c = (int)(t2 & 127); int b = (int)(t2 >> 7);
  float ys = ho * s;
  int y0 = (int)ys; float wy = ys - y0;
  int y1 = min(y0 + 1, 63);
  const float* p = in + (((long)(b * 128 + c)) << 12);
  int4 val; unsigned short* vs = (unsigned short*)&val;
#pragma unroll
  for (int j = 0; j < 8; j++) {
    int wo = seg * 8 + j;
    float xs = wo * s;
    int x0 = (int)xs; float wx = xs - x0;
    int x1 = min(x0 + 1, 63);
    float v00 = p[(y0 << 6) + x0], v01 = p[(y0 << 6) + x1];
    float v10 = p[(y1 << 6) + x0], v11 = p[(y1 << 6) + x1];
    float r0 = v00 + (v01 - v00) * wx;
    float r1 = v10 + (v11 - v10) * wx;
    vs[j] = f2bf(r0 + (r1 - r0) * wy);
  }
  *(int4*)(out + (((long)(b * 128 + c)) << 14) + (ho << 7) + seg * 8) = val;
}

// ============================================================================
// MFMA implicit-GEMM 3x3 conv, det-branch variant (COB split, weights via LDS).
// ============================================================================
template <int W_, int CIN, int COB, int FC, int FN>
__global__ __launch_bounds__(256) void conv2_k(
    const unsigned short* __restrict__ xin, const unsigned short* __restrict__ wpk,
    float* __restrict__ out, int H) {
  constexpr int CP = 40;
  __shared__ unsigned short wbuf[3 * COB * CP];
  __shared__ unsigned short rbuf[(W_ + 2) * CP];
  int h = blockIdx.x, b = blockIdx.y, cb = blockIdx.z;
  int t = threadIdx.x;
  int wid = t >> 6, lane = t & 63;
  int co0 = (wid >> 1) * (FC * 16);
  int n0 = (wid & 1) * (FN * 16);
  int lm = lane & 15, lk = lane >> 4;
  f32x4 acc[FC][FN];
#pragma unroll
  for (int i = 0; i < FC; i++)
#pragma unroll
    for (int j = 0; j < FN; j++) acc[i][j] = (f32x4){0.f, 0.f, 0.f, 0.f};

  constexpr int WEL = 3 * COB * 32 / 8;
  constexpr int REL = (W_ + 2) * 32 / 8;

  for (int c0 = 0; c0 < CIN; c0 += 32) {
    for (int ky = 0; ky < 3; ky++) {
      int hr = h + ky - 1;
      __syncthreads();
      for (int i = t; i < WEL + REL; i += 256) {
        if (i < WEL) {
          int e = i * 8;
          int kx = e / (COB * 32);
          int rem = e - kx * (COB * 32);
          int co = rem >> 5, ci = rem & 31;
          const unsigned short* g =
              wpk + ((long)((ky * 3 + kx) * 128 + cb * COB + co)) * CIN + c0 + ci;
          *(int4*)&wbuf[(kx * COB + co) * CP + ci] = *(const int4*)g;
        } else {
          int e = (i - WEL) * 8;
          int col = e >> 5, ci = e & 31;
          int gc = col - 1;
          int4 v = {0, 0, 0, 0};
          if (hr >= 0 && hr < H && gc >= 0 && gc < W_)
            v = *(const int4*)(xin + ((long)((b * H + hr) * W_ + gc)) * CIN + c0 + ci);
          *(int4*)&rbuf[col * CP + ci] = v;
        }
      }
      __syncthreads();
#pragma unroll
      for (int kx = 0; kx < 3; kx++) {
        short8 afr[FC], bfr[FN];
#pragma unroll
        for (int i = 0; i < FC; i++)
          afr[i] = *(const short8*)&wbuf[(kx * COB + co0 + i * 16 + lm) * CP + lk * 8];
#pragma unroll
        for (int j = 0; j < FN; j++)
          bfr[j] = *(const short8*)&rbuf[(n0 + j * 16 + lm + kx) * CP + lk * 8];
#pragma unroll
        for (int i = 0; i < FC; i++)
#pragma unroll
          for (int j = 0; j < FN; j++)
            acc[i][j] = __builtin_amdgcn_mfma_f32_16x16x32_bf16(afr[i], bfr[j], acc[i][j], 0, 0, 0);
      }
    }
  }
#pragma unroll
  for (int i = 0; i < FC; i++) {
#pragma unroll
    for (int r = 0; r < 4; r++) {
      int col = cb * COB + co0 + i * 16 + lk * 4 + r;
      long obase = (((long)(b * 128 + col)) * H + h) * W_;
#pragma unroll
      for (int j = 0; j < FN; j++)
        out[obase + n0 + j * 16 + lm] = acc[i][j][r];
    }
  }
}

// ============================================================================
// MFMA implicit-GEMM 3x3 conv v3 (R9): per c0 chunk stage ALL 3 input rows in
// one barrier-pair (8 barriers for CIN=256 vs 24 in conv2); A-fragments come
// DIRECTLY from global (weights are L2-resident, 0.3-0.6MB) and are preloaded
// before the barrier so they overlap the row staging. 72 MFMA/wave/barrier.
// LDS = rows only (31KB). grid (H, B, 128/COB), block 256 (4 waves 2co x 2n).
// ============================================================================
template <int W_, int CIN, int COB, int FC, int FN>
__global__ __launch_bounds__(256) void conv3_k(
    const unsigned short* __restrict__ xin, const unsigned short* __restrict__ wpk,
    float* __restrict__ out, int H) {
  constexpr int CP = 40;
  __shared__ unsigned short rbuf[3 * (W_ + 2) * CP];
  int h = blockIdx.x, b = blockIdx.y, cb = blockIdx.z;
  int t = threadIdx.x;
  int wid = t >> 6, lane = t & 63;
  int co0 = cb * COB + (wid >> 1) * (FC * 16);
  int n0 = (wid & 1) * (FN * 16);
  int lm = lane & 15, lk = lane >> 4;
  f32x4 acc[FC][FN];
#pragma unroll
  for (int i = 0; i < FC; i++)
#pragma unroll
    for (int j = 0; j < FN; j++) acc[i][j] = (f32x4){0.f, 0.f, 0.f, 0.f};

  constexpr int RW = W_ + 2;
  constexpr int REL = 3 * RW * 32 / 8;  // int4 elements per c0 chunk

  for (int c0 = 0; c0 < CIN; c0 += 32) {
    // preload A fragments from global (L2-hot); overlaps row staging below
    short8 afr[9][FC];
#pragma unroll
    for (int kk = 0; kk < 9; kk++)
#pragma unroll
      for (int i = 0; i < FC; i++)
        afr[kk][i] = *(const short8*)(wpk +
            ((long)(kk * 128 + co0 + i * 16 + lm)) * CIN + c0 + lk * 8);
    __syncthreads();
    for (int i = t; i < REL; i += 256) {
      int r = i / (RW * 4);
      int rem = i - r * (RW * 4);
      int col = rem >> 2, q = rem & 3;
      int hr = h + r - 1, gc = col - 1;
      int4 v = {0, 0, 0, 0};
      if (hr >= 0 && hr < H && gc >= 0 && gc < W_)
        v = *(const int4*)(xin + ((long)((b * H + hr) * W_ + gc)) * CIN + c0 + q * 8);
      *(int4*)&rbuf[(r * RW + col) * CP + q * 8] = v;
    }
    __syncthreads();
#pragma unroll
    for (int ky = 0; ky < 3; ky++) {
#pragma unroll
      for (int kx = 0; kx < 3; kx++) {
        short8 bfr[FN];
#pragma unroll
        for (int j = 0; j < FN; j++)
          bfr[j] = *(const short8*)&rbuf[(ky * RW + n0 + j * 16 + lm + kx) * CP + lk * 8];
#pragma unroll
        for (int i = 0; i < FC; i++)
#pragma unroll
          for (int j = 0; j < FN; j++)
            acc[i][j] = __builtin_amdgcn_mfma_f32_16x16x32_bf16(afr[ky * 3 + kx][i], bfr[j],
                                                                acc[i][j], 0, 0, 0);
      }
    }
  }
#pragma unroll
  for (int i = 0; i < FC; i++) {
#pragma unroll
    for (int r = 0; r < 4; r++) {
      int col = co0 + i * 16 + lk * 4 + r;
      long obase = (((long)(b * 128 + col)) * H + h) * W_;
#pragma unroll
      for (int j = 0; j < FN; j++)
        out[obase + n0 + j * 16 + lm] = acc[i][j][r];
    }
  }
}

// ============================================================================
// stats reductions (BW-bound, 1-2 atomics per BLOCK)
// ============================================================================
__global__ void gn_sums_k(const float* __restrict__ x, float* __restrict__ sums,
                          int Ctot, int coff, int cpg, int HW, int goff) {
  int bg = blockIdx.x; int b = bg >> 3, g = bg & 7;
  const float* p = x + ((long)b * Ctot + coff + (long)g * cpg) * HW;
  long len = (long)cpg * HW;
  long chunk = len / gridDim.y;
  long s = (long)blockIdx.y * chunk, e = s + chunk;
  float s0 = 0.f, s1 = 0.f;
  for (long i = s + threadIdx.x; i < e; i += 256) {
    float v = p[i]; s0 += v; s1 += v * v;
  }
  __shared__ float r0[256], r1[256];
  int t = threadIdx.x;
  r0[t] = s0; r1[t] = s1;
  __syncthreads();
  for (int off = 128; off > 0; off >>= 1) {
    if (t < off) { r0[t] += r0[t + off]; r1[t] += r1[t + off]; }
    __syncthreads();
  }
  if (t == 0) {
    int gi = b * 16 + goff + g;
    atomicAdd(&sums[2 * gi], r0[0]);
    atomicAdd(&sums[2 * gi + 1], r1[0]);
  }
}

__global__ void bn_sums_k(const float* __restrict__ x, float* __restrict__ sums, int C) {
  int c = blockIdx.x;
  long total = 4L << 14;
  long chunk = total / gridDim.y;
  long s = (long)blockIdx.y * chunk, e = s + chunk;
  float s0 = 0.f, s1 = 0.f;
  for (long i = s + threadIdx.x; i < e; i += 256) {
    int b = (int)(i >> 14); int hw = (int)(i & 16383);
    float v = x[(((long)b * C + c) << 14) + hw];
    s0 += v; s1 += v * v;
  }
  __shared__ float r0[256], r1[256];
  int t = threadIdx.x;
  r0[t] = s0; r1[t] = s1;
  __syncthreads();
  for (int off = 128; off > 0; off >>= 1) {
    if (t < off) { r0[t] += r0[t + off]; r1[t] += r1[t + off]; }
    __syncthreads();
  }
  if (t == 0) { atomicAdd(&sums[2 * c], r0[0]); atomicAdd(&sums[2 * c + 1], r1[0]); }
}

// ============================================================================
// IDWT(haar) fused with GN+tanh+scale; stats finalized inline from s_det
// ============================================================================
__global__ void idwt_k(const float* __restrict__ det, const float* __restrict__ sd,
                       const float* __restrict__ gll, const float* __restrict__ bll,
                       const float* __restrict__ ghi, const float* __restrict__ bhi,
                       const float* __restrict__ wsc, float* __restrict__ rec) {
  long idx = ((long)blockIdx.x << 8) + threadIdx.x;
  if (idx >= (long)4 * 32 * 64 * 64) return;
  int j = (int)(idx & 63); long t = idx >> 6;
  int i = (int)(t & 63); t >>= 6;
  int c = (int)(t & 31); int b = (int)(t >> 5);
  float s = wsc[0]; s = fminf(fmaxf(s, 1.f), 5.f);
  const float icll = 1.f / 16384.f, ichi = 1.f / 49152.f;
  const float* dp = det + ((long)b << 19);
  long sp = ((long)i << 6) + j;
  int gi = b * 16 + (c >> 2);
  float m = sd[2 * gi] * icll;
  float r = rsqrtf(fmaxf(sd[2 * gi + 1] * icll - m * m, 0.f) + EPSV);
  float ll = tanhf((dp[((long)c << 12) + sp] - m) * r * gll[c] + bll[c]) * s;
  int hc = c; gi = b * 16 + 8 + hc / 12;
  m = sd[2 * gi] * ichi; r = rsqrtf(fmaxf(sd[2 * gi + 1] * ichi - m * m, 0.f) + EPSV);
  float lh = tanhf((dp[((long)(32 + hc) << 12) + sp] - m) * r * ghi[hc] + bhi[hc]) * s;
  hc = 32 + c; gi = b * 16 + 8 + hc / 12;
  m = sd[2 * gi] * ichi; r = rsqrtf(fmaxf(sd[2 * gi + 1] * ichi - m * m, 0.f) + EPSV);
  float hl = tanhf((dp[((long)(32 + hc) << 12) + sp] - m) * r * ghi[hc] + bhi[hc]) * s;
  hc = 64 + c; gi = b * 16 + 8 + hc / 12;
  m = sd[2 * gi] * ichi; r = rsqrtf(fmaxf(sd[2 * gi + 1] * ichi - m * m, 0.f) + EPSV);
  float hh = tanhf((dp[((long)(32 + hc) << 12) + sp] - m) * r * ghi[hc] + bhi[hc]) * s;
  float x00 = (ll + lh + hl + hh) * 0.5f;
  float x01 = (ll - lh + hl - hh) * 0.5f;
  float x10 = (ll + lh - hl - hh) * 0.5f;
  float x11 = (ll - lh - hl + hh) * 0.5f;
  float* rp = rec + (((long)b * 32 + c) << 14) + ((long)i << 8) + (j << 1);
  rp[0] = x00; rp[1] = x01; rp[128] = x10; rp[129] = x11;
}

// ============================================================================
// skip_up_raw = W_adj (128x32) @ rec; fused GN-sums accumulation
// ============================================================================
__global__ __launch_bounds__(256) void adj_k(const float* __restrict__ rec,
                                             const float* __restrict__ Wadj,
                                             float* __restrict__ out,
                                             float* __restrict__ gsums) {
  __shared__ float ls[32][256];
  int n0 = blockIdx.x << 8;
  int o0 = blockIdx.y << 4;
  int b = blockIdx.z;
  int t = threadIdx.x;
  for (int idx = t; idx < 32 * 256; idx += 256) {
    int c = idx >> 8, n = idx & 255;
    ls[c][n] = rec[(((long)b * 32 + c) << 14) + n0 + n];
  }
  __syncthreads();
  float acc[16];
#pragma unroll
  for (int i = 0; i < 16; i++) acc[i] = 0.f;
  for (int c = 0; c < 32; c++) {
    float v = ls[c][t];
#pragma unroll
    for (int i = 0; i < 16; i++) acc[i] += v * Wadj[(o0 + i) * 32 + c];
  }
  float s0 = 0.f, s1 = 0.f;
#pragma unroll
  for (int i = 0; i < 16; i++) {
    out[(((long)b * 128 + o0 + i) << 14) + n0 + t] = acc[i];
    s0 += acc[i]; s1 += acc[i] * acc[i];
  }
  __syncthreads();
  float* red = (float*)ls;
  red[t] = s0; red[256 + t] = s1;
  __syncthreads();
  for (int off = 128; off > 0; off >>= 1) {
    if (t < off) { red[t] += red[t + off]; red[256 + t] += red[256 + t + off]; }
    __syncthreads();
  }
  if (t == 0) {
    int gi = b * 8 + (o0 >> 4);
    atomicAdd(&gsums[2 * gi], red[0]);
    atomicAdd(&gsums[2 * gi + 1], red[256]);
  }
}

// ============================================================================
// GN relu apply (skip_up), vectorized 8/thread, stats inline from sums
// ============================================================================
__global__ void gn_relu_k(float* __restrict__ x, const float* __restrict__ sums,
                          const float* __restrict__ gamma, const float* __restrict__ beta) {
  long i0 = ((long)blockIdx.x * 256 + threadIdx.x) * 8;
  int ch = (int)((i0 >> 14) & 127);
  int b = (int)(i0 >> 21);
  int sidx = b * 8 + (ch >> 4);
  const float ic = 1.f / 262144.f;
  float m = sums[2 * sidx] * ic;
  float r = rsqrtf(fmaxf(sums[2 * sidx + 1] * ic - m * m, 0.f) + EPSV);
  float ga = gamma[ch] * r, be = beta[ch] - m * r * gamma[ch];
#pragma unroll
  for (int j = 0; j < 8; j++) {
    float v = fmaxf(x[i0 + j] * ga + be, 0.f);
    x[i0 + j] = v;
  }
}

// BN relu apply (+add +bf16 NCHW copy), 8/thread
__global__ void bn_apply8_k(float* __restrict__ x, const float* __restrict__ sums,
                            const float* __restrict__ gamma, const float* __restrict__ beta,
                            const float* __restrict__ add, unsigned short* __restrict__ obf) {
  long i0 = ((long)blockIdx.x * 256 + threadIdx.x) * 8;
  int ch = (int)((i0 >> 14) & 127);
  const float ic = 1.f / 65536.f;
  float m = sums[2 * ch] * ic;
  float r = rsqrtf(fmaxf(sums[2 * ch + 1] * ic - m * m, 0.f) + EPSV);
  float ga = gamma[ch] * r, be = beta[ch] - m * r * gamma[ch];
  int4 ov; unsigned short* os = (unsigned short*)&ov;
#pragma unroll
  for (int j = 0; j < 8; j++) {
    float v = fmaxf(x[i0 + j] * ga + be, 0.f);
    if (add) v += add[i0 + j];
    x[i0 + j] = v;
    os[j] = f2bf(v);
  }
  if (obf) *(int4*)(obf + i0) = ov;
}

// GN silu apply + add merged (att_in), accumulate next-GN sums. 8/thread.
__global__ void gn_silu_add_k(float* __restrict__ x, const float* __restrict__ sums,
                              const float* __restrict__ gamma, const float* __restrict__ beta,
                              const float* __restrict__ add, float* __restrict__ osums) {
  long i0 = ((long)blockIdx.x * 256 + threadIdx.x) * 8;
  int ch = (int)((i0 >> 14) & 127);
  int b = (int)(i0 >> 21);
  int sidx = b * 8 + (ch >> 4);
  const float ic = 1.f / 262144.f;
  float m = sums[2 * sidx] * ic;
  float r = rsqrtf(fmaxf(sums[2 * sidx + 1] * ic - m * m, 0.f) + EPSV);
  float ga = gamma[ch] * r, be = beta[ch] - m * r * gamma[ch];
  float s0 = 0.f, s1 = 0.f;
#pragma unroll
  for (int j = 0; j < 8; j++) {
    float v = x[i0 + j] * ga + be;
    v = v / (1.f + expf(-v));
    v += add[i0 + j];
    x[i0 + j] = v;
    s0 += v; s1 += v * v;
  }
  __shared__ float r0[256], r1[256];
  int t = threadIdx.x;
  r0[t] = s0; r1[t] = s1;
  __syncthreads();
  for (int off = 128; off > 0; off >>= 1) {
    if (t < off) { r0[t] += r0[t + off]; r1[t] += r1[t + off]; }
    __syncthreads();
  }
  if (t == 0) {
    atomicAdd(&osums[2 * sidx], r0[0]);
    atomicAdd(&osums[2 * sidx + 1], r1[0]);
  }
}

// ============================================================================
// colsum of 4 bf16-NCHW buffers -> Sall[2048]
// ============================================================================
__global__ void colsum4_k(const unsigned short* __restrict__ m, const unsigned short* __restrict__ f0,
                          const unsigned short* __restrict__ f1, const unsigned short* __restrict__ f2,
                          float* __restrict__ S) {
  int bc = blockIdx.x, which = blockIdx.y;
  const unsigned short* p = (which == 0 ? m : which == 1 ? f0 : which == 2 ? f1 : f2) + ((long)bc << 14);
  float a = 0.f;
  for (int i = threadIdx.x; i < 2048; i += 256) {
    int4 v = *(const int4*)(p + i * 8);
    unsigned short* vs = (unsigned short*)&v;
#pragma unroll
    for (int j = 0; j < 8; j++) a += bf2f(vs[j]);
  }
  __shared__ float red[256];
  red[threadIdx.x] = a;
  __syncthreads();
  for (int off = 128; off > 0; off >>= 1) {
    if (threadIdx.x < off) red[threadIdx.x] += red[threadIdx.x + off];
    __syncthreads();
  }
  if (threadIdx.x == 0) S[which * 512 + bc] = red[0];
}

// ============================================================================
// Gram via MFMA: Gpart[nc][p*4+b][c][c'] partial over 512-n chunk.
// ============================================================================
__global__ __launch_bounds__(256) void gram_mfma_k(
    const unsigned short* __restrict__ mbf, const unsigned short* __restrict__ f0,
    const unsigned short* __restrict__ f1, const unsigned short* __restrict__ f2,
    float* __restrict__ Gpart) {
  constexpr int CP = 40;
  __shared__ unsigned short As[128 * CP], Bs[128 * CP];
  int nc = blockIdx.x, p = blockIdx.y, b = blockIdx.z;
  const unsigned short* fp = (p == 0 ? f0 : p == 1 ? f1 : f2);
  const unsigned short* ma = mbf + ((long)b << 21);
  const unsigned short* fa = fp + ((long)b << 21);
  int t = threadIdx.x;
  int wid = t >> 6, lane = t & 63;
  int c0 = (wid >> 1) << 6;
  int cp0 = (wid & 1) << 6;
  int lm = lane & 15, lk = lane >> 4;
  f32x4 acc[4][4];
#pragma unroll
  for (int i = 0; i < 4; i++)
#pragma unroll
    for (int j = 0; j < 4; j++) acc[i][j] = (f32x4){0.f, 0.f, 0.f, 0.f};
  for (int ks = 0; ks < 16; ks++) {
    int n = (nc << 9) + (ks << 5);
    __syncthreads();
#pragma unroll
    for (int i = 0; i < 2; i++) {
      int idx = t + (i << 8);
      int row = idx >> 2, q = idx & 3;
      *(int4*)&As[row * CP + q * 8] = *(const int4*)(ma + ((long)row << 14) + n + q * 8);
      *(int4*)&Bs[row * CP + q * 8] = *(const int4*)(fa + ((long)row << 14) + n + q * 8);
    }
    __syncthreads();
    short8 af[4], bfr[4];
#pragma unroll
    for (int i = 0; i < 4; i++) af[i] = *(const short8*)&As[(c0 + i * 16 + lm) * CP + lk * 8];
#pragma unroll
    for (int j = 0; j < 4; j++) bfr[j] = *(const short8*)&Bs[(cp0 + j * 16 + lm) * CP + lk * 8];
#pragma unroll
    for (int i = 0; i < 4; i++)
#pragma unroll
      for (int j = 0; j < 4; j++)
        acc[i][j] = __builtin_amdgcn_mfma_f32_16x16x32_bf16(af[i], bfr[j], acc[i][j], 0, 0, 0);
  }
  float* Gp = Gpart + (((long)(nc * 12 + p * 4 + b)) << 14);
#pragma unroll
  for (int i = 0; i < 4; i++)
#pragma unroll
    for (int j = 0; j < 4; j++) {
      int cp = cp0 + j * 16 + lm;
#pragma unroll
      for (int r = 0; r < 4; r++) {
        int c = c0 + i * 16 + lk * 4 + r;
        Gp[c * 128 + cp] = acc[i][j][r];
      }
    }
}

// reduce 32 partials -> G
__global__ void gred_k(const float* __restrict__ Gpart, float* __restrict__ G) {
  int cell = blockIdx.x * 256 + threadIdx.x;  // 196608
  int pb = cell >> 14, rem = cell & 16383;
  float a = 0.f;
  for (int nc = 0; nc < 32; nc++) a += Gpart[(((long)(nc * 12 + pb)) << 14) + rem];
  G[cell] = a;
}

// ============================================================================
// attention logits from Gram + softmax
// ============================================================================
__global__ __launch_bounds__(256) void attn_k(const float* __restrict__ G,
                                              const float* __restrict__ Sall,
                                              const float* __restrict__ Wq,
                                              const float* __restrict__ bq,
                                              const float* __restrict__ Wk,
                                              const float* __restrict__ bk,
                                              float* __restrict__ attn) {
  int h = blockIdx.x, b = blockIdx.y, p = blockIdx.z;
  __shared__ float T[32][129];
  __shared__ float QS2[32], KS1[32];
  __shared__ float L[32][33];
  const float* S2 = Sall;
  const float* S1 = Sall + 512;
  const float* Gpb = G + ((long)(p * 4 + b) << 14);
  const float* Wqp = Wq + p * 16384;
  const float* Wkp = Wk + p * 16384;
  int t = threadIdx.x;
  if (t < 32) {
    float a = 0.f;
    for (int c = 0; c < 128; c++) a += Wqp[(h * 32 + t) * 128 + c] * S2[b * 128 + c];
    QS2[t] = a;
  } else if (t < 64) {
    int e = t - 32;
    float a = 0.f;
    for (int c = 0; c < 128; c++) a += Wkp[(h * 32 + e) * 128 + c] * S1[(p * 4 + b) * 128 + c];
    KS1[e] = a;
  }
  __syncthreads();
  for (int ii = t; ii < 4096; ii += 256) {
    int d = ii >> 7, cp = ii & 127;
    float a = 0.f;
    for (int c = 0; c < 128; c++) a += Wqp[(h * 32 + d) * 128 + c] * Gpb[c * 128 + cp];
    T[d][cp] = a;
  }
  __syncthreads();
  const float scale = 0.17677669529663687f;
  for (int ii = t; ii < 1024; ii += 256) {
    int d = ii >> 5, e = ii & 31;
    float a = 0.f;
    for (int cp = 0; cp < 128; cp++) a += T[d][cp] * Wkp[(h * 32 + e) * 128 + cp];
    float bqv = bq[p * 128 + h * 32 + d], bkv = bk[p * 128 + h * 32 + e];
    a += bqv * KS1[e] + bkv * QS2[d] + 16384.f * bqv * bkv;
    L[d][e] = a * scale;
  }
  __syncthreads();
  if (t < 32) {
    float mx = -1e30f;
    for (int e = 0; e < 32; e++) mx = fmaxf(mx, L[t][e]);
    float sum = 0.f;
    for (int e = 0; e < 32; e++) { float ev = expf(L[t][e] - mx); L[t][e] = ev; sum += ev; }
    float inv = 1.f / sum;
    float* ap = attn + ((((long)(p * 4 + b)) * 4 + h) * 32 + t) * 32;
    for (int e = 0; e < 32; e++) ap[e] = L[t][e] * inv;
  }
}

// ============================================================================
// M + cbias
// ============================================================================
__global__ void m_k(const float* __restrict__ Wf, const float* __restrict__ attn,
                    const float* __restrict__ bv, float* __restrict__ M,
                    float* __restrict__ cbias) {
  int o = blockIdx.x, b = blockIdx.y, p = blockIdx.z;
  int ap = threadIdx.x;
  int h = ap >> 5;
  const float* at = attn + (((long)(p * 4 + b)) * 4 + h) * 1024;
  const float* wrow = Wf + o * 384 + p * 128 + h * 32;
  int e = ap & 31;
  float acc = 0.f;
  for (int d = 0; d < 32; d++) acc += wrow[d] * at[d * 32 + e];
  M[(((long)(p * 4 + b)) * 128 + o) * 128 + ap] = acc;
  __shared__ float red[128];
  red[ap] = acc * bv[p * 128 + ap];
  __syncthreads();
  for (int off = 64; off > 0; off >>= 1) {
    if (ap < off) red[ap] += red[ap + off];
    __syncthreads();
  }
  if (ap == 0) atomicAdd(&cbias[b * 128 + o], red[0]);
}

// Weff bf16: [b][o][384] with k = p*128+c
__global__ void weff_k(const float* __restrict__ M, const float* __restrict__ Wv,
                       unsigned short* __restrict__ Weff) {
  int o = blockIdx.x, b = blockIdx.y, p = blockIdx.z, c = threadIdx.x;
  const float* mrow = M + (((long)(p * 4 + b)) * 128 + o) * 128;
  const float* wv = Wv + p * 16384;
  float acc = 0.f;
  for (int a = 0; a < 128; a++) acc += mrow[a] * wv[a * 128 + c];
  Weff[((long)(b * 128 + o)) * 384 + p * 128 + c] = f2bf(acc);
}

// ============================================================================
// fused_pre = Weff @ feats, B from NHWC bf16 (straight int4 staging).
// grid (128 nchunks, 2 ob, 4 b), block 256 (waves 2co x 2n). Fused GN sums.
// ============================================================================
__global__ __launch_bounds__(256) void fuse_mfma_k(
    const unsigned short* __restrict__ Wef, const unsigned short* __restrict__ f0t,
    const unsigned short* __restrict__ f1t, const unsigned short* __restrict__ f2t,
    const float* __restrict__ bf_, const float* __restrict__ cbias,
    float* __restrict__ out, float* __restrict__ gsums) {
  constexpr int CP = 40;
  __shared__ unsigned short As[64 * CP], Bs[128 * CP];
  __shared__ float sred[8];
  int nc = blockIdx.x, ob = blockIdx.y, b = blockIdx.z;
  int t = threadIdx.x;
  int wid = t >> 6, lane = t & 63;
  int o0 = (wid >> 1) * 32;
  int n0 = (wid & 1) * 64;
  int lm = lane & 15, lk = lane >> 4;
  if (t < 8) sred[t] = 0.f;
  f32x4 acc[2][4];
#pragma unroll
  for (int i = 0; i < 2; i++)
#pragma unroll
    for (int j = 0; j < 4; j++) acc[i][j] = (f32x4){0.f, 0.f, 0.f, 0.f};
  for (int kp = 0; kp < 12; kp++) {
    int k0 = kp << 5;
    int p = k0 >> 7, cc0 = k0 & 127;
    const unsigned short* ft = (p == 0 ? f0t : p == 1 ? f1t : f2t);
    __syncthreads();
    for (int i = t; i < 768; i += 256) {
      if (i < 256) {
        int row = i >> 2, q = i & 3;
        *(int4*)&As[row * CP + q * 8] =
            *(const int4*)(Wef + ((long)(b * 128 + ob * 64 + row)) * 384 + k0 + q * 8);
      } else {
        int j2 = i - 256;
        int n = j2 >> 2, q = j2 & 3;
        *(int4*)&Bs[n * CP + q * 8] =
            *(const int4*)(ft + ((long)(b * 16384 + nc * 128 + n)) * 128 + cc0 + q * 8);
      }
    }
    __syncthreads();
    short8 af[2], bfr[4];
#pragma unroll
    for (int i = 0; i < 2; i++) af[i] = *(const short8*)&As[(o0 + i * 16 + lm) * CP + lk * 8];
#pragma unroll
    for (int j = 0; j < 4; j++) bfr[j] = *(const short8*)&Bs[(n0 + j * 16 + lm) * CP + lk * 8];
#pragma unroll
    for (int i = 0; i < 2; i++)
#pragma unroll
      for (int j = 0; j < 4; j++)
        acc[i][j] = __builtin_amdgcn_mfma_f32_16x16x32_bf16(af[i], bfr[j], acc[i][j], 0, 0, 0);
  }
#pragma unroll
  for (int i = 0; i < 2; i++) {
    float s0 = 0.f, s1 = 0.f;
#pragma unroll
    for (int r = 0; r < 4; r++) {
      int o = ob * 64 + o0 + i * 16 + lk * 4 + r;
      float bias = bf_[o] + cbias[b * 128 + o];
#pragma unroll
      for (int j = 0; j < 4; j++) {
        int n = (nc << 7) + n0 + j * 16 + lm;
        float v = acc[i][j][r] + bias;
        out[(((long)(b * 128 + o)) << 14) + n] = v;
        s0 += v; s1 += v * v;
      }
    }
#pragma unroll
    for (int off = 1; off < 64; off <<= 1) {
      s0 += __shfl_xor(s0, off, 64);
      s1 += __shfl_xor(s1, off, 64);
    }
    if (lane == 0) {
      int gl = (o0 >> 4) + i;  // 0..3
      atomicAdd(&sred[2 * gl], s0);
      atomicAdd(&sred[2 * gl + 1], s1);
    }
  }
  __syncthreads();
  if (t < 8) {
    int g = b * 8 + ob * 4 + (t >> 1);
    atomicAdd(&gsums[2 * g + (t & 1)], sred[t]);
  }
}

// ============================================================================
extern "C" void kernel_launch(void* const* d_in, const int* in_sizes, int n_in,
                              void* d_out, int out_size, void* d_ws, size_t ws_size,
                              hipStream_t stream) {
  const float* x      = (const float*)d_in[0];
  const float* sdet   = (const float*)d_in[1];
  const float* sstru  = (const float*)d_in[2];
  const float* sglob  = (const float*)d_in[3];
  const float* W_up   = (const float*)d_in[4];
  const float* bnug   = (const float*)d_in[5];
  const float* bnub   = (const float*)d_in[6];
  const float* W_ll   = (const float*)d_in[7];
  const float* gllg   = (const float*)d_in[8];
  const float* gllb   = (const float*)d_in[9];
  const float* W_hi   = (const float*)d_in[10];
  const float* ghig   = (const float*)d_in[11];
  const float* ghib   = (const float*)d_in[12];
  const float* wsc    = (const float*)d_in[13];
  const float* W_adj  = (const float*)d_in[14];
  const float* gadjg  = (const float*)d_in[15];
  const float* gadjb  = (const float*)d_in[16];
  const float* Wq     = (const float*)d_in[17];
  const float* bq     = (const float*)d_in[18];
  const float* Wk     = (const float*)d_in[19];
  const float* bk     = (const float*)d_in[20];
  const float* Wv     = (const float*)d_in[21];
  const float* bv     = (const float*)d_in[22];
  const float* W_fu   = (const float*)d_in[23];
  const float* b_fu   = (const float*)d_in[24];
  const float* gfug   = (const float*)d_in[25];
  const float* gfub   = (const float*)d_in[26];
  const float* goug   = (const float*)d_in[27];
  const float* goub   = (const float*)d_in[28];
  const float* W_r1   = (const float*)d_in[29];
  const float* bn1g   = (const float*)d_in[30];
  const float* bn1b   = (const float*)d_in[31];
  const float* W_r2   = (const float*)d_in[32];
  const float* bn2g   = (const float*)d_in[33];
  const float* bn2b   = (const float*)d_in[34];
  float* out = (float*)d_out;

  float* ws = (float*)d_ws;
  size_t off = 0;
  auto alloc = [&](size_t n) { float* p = ws + off; off += n; return p; };
  float* bufA = alloc(8388608);   // det+rec early; Gpart mid; fused_pre/att_in late
  float* det  = bufA;             // (4,128,64,64)
  float* rec  = bufA + 2097152;   // (4,32,128,128)
  float* Gpart = bufA;            // 32 x 12 x 16384 = 6.29M (after rec dead)
  float* bufB = alloc(8388608);   // conv_up out -> merged; later r1
  float* bufC = alloc(8388608);   // skip_up fp32; later f1t+f2t (bf16)
  unsigned short* f1t = (unsigned short*)bufC;            // NHWC bf16 sstru
  unsigned short* f2t = (unsigned short*)bufC + 8388608;  // NHWC bf16 glob
  unsigned short* xbf = (unsigned short*)alloc(8388608);  // NHWC bf16 conv inputs
  unsigned short* f0t = (unsigned short*)alloc(4194304);  // NHWC bf16 skip_up
  unsigned short* mbf = (unsigned short*)alloc(4194304);  // merged bf16 NCHW
  unsigned short* f0  = (unsigned short*)alloc(4194304);  // skip_up bf16 NCHW
  unsigned short* f1  = (unsigned short*)alloc(4194304);  // sstru bf16 NCHW
  unsigned short* f2  = (unsigned short*)alloc(4194304);  // glob-resized bf16 NCHW
  float* Gm   = alloc(196608);
  unsigned short* wpk_up = (unsigned short*)alloc(147456);
  unsigned short* wpk_r1 = (unsigned short*)alloc(73728);
  unsigned short* wpk_r2 = (unsigned short*)alloc(73728);
  unsigned short* wpk_dt = (unsigned short*)alloc(36864);
  unsigned short* wefb   = (unsigned short*)alloc(98304);
  float* Sall = alloc(2048);
  float* attb = alloc(49152);
  float* Mb   = alloc(196608);
  float* zr = alloc(1600);
  float* cb      = zr;            // 512
  float* s_det   = zr + 512;      // 128
  float* s_adj   = zr + 640;      // 64
  float* s_bnup  = zr + 704;      // 256
  float* s_fuse  = zr + 960;      // 64
  float* s_gnout = zr + 1024;     // 64
  float* s_bn1   = zr + 1088;     // 256
  float* s_bn2   = zr + 1344;     // 256

  const float s63 = 63.f / 127.f;

  hipMemsetAsync(zr, 0, 1600 * sizeof(float), stream);
  packall_k<<<2880, 256, 0, stream>>>(W_up, W_r1, W_r2, W_ll, W_hi,
                                      wpk_up, wpk_r1, wpk_r2, wpk_dt);

  // ---- detail branch
  t_nhwc_k<<<dim3(64, 4, 4), 256, 0, stream>>>(sdet, xbf, nullptr, 128, 4096);
  conv2_k<64, 128, 32, 1, 2><<<dim3(64, 4, 4), 256, 0, stream>>>(xbf, wpk_dt, det, 64);
  gn_sums_k<<<dim3(32, 4), 256, 0, stream>>>(det, s_det, 128, 0, 4, 4096, 0);
  gn_sums_k<<<dim3(32, 8), 256, 0, stream>>>(det, s_det, 128, 32, 12, 4096, 8);
  idwt_k<<<2048, 256, 0, stream>>>(det, s_det, gllg, gllb, ghig, ghib, wsc, rec);

  // ---- skip_up = relu(GN(W_adj @ rec))
  adj_k<<<dim3(64, 8, 4), 256, 0, stream>>>(rec, W_adj, bufC, s_adj);
  gn_relu_k<<<4096, 256, 0, stream>>>(bufC, s_adj, gadjg, gadjb);

  // ---- merged = relu(BN(conv_up(resize(x)))) + skip_up
  resize_t_k<<<dim3(128, 8, 4), 256, 0, stream>>>(x, xbf, 256, s63);
  conv3_k<128, 256, 64, 2, 4><<<dim3(128, 4, 2), 256, 0, stream>>>(xbf, wpk_up, bufB, 128);
  bn_sums_k<<<dim3(128, 16), 256, 0, stream>>>(bufB, s_bnup, 128);
  bn_apply8_k<<<4096, 256, 0, stream>>>(bufB, s_bnup, bnug, bnub, bufC, mbf);

  // ---- feats bf16 copies (NCHW for gram + NHWC for fuse, dual-write)
  t_nhwc_k<<<dim3(256, 4, 4), 256, 0, stream>>>(bufC, f0t, f0, 128, 16384);
  t_nhwc_k<<<dim3(256, 4, 4), 256, 0, stream>>>(sstru, f1t, f1, 128, 16384);
  resize_nchwbf_k<<<4096, 256, 0, stream>>>(sglob, f2, s63);
  resize_t_k<<<dim3(128, 4, 4), 256, 0, stream>>>(sglob, f2t, 128, s63);

  // ---- attention via Gram matrices (MFMA)
  colsum4_k<<<dim3(512, 4), 256, 0, stream>>>(mbf, f0, f1, f2, Sall);
  gram_mfma_k<<<dim3(32, 3, 4), 256, 0, stream>>>(mbf, f0, f1, f2, Gpart);
  gred_k<<<768, 256, 0, stream>>>(Gpart, Gm);
  attn_k<<<dim3(4, 4, 3), 256, 0, stream>>>(Gm, Sall, Wq, bq, Wk, bk, attb);

  // ---- collapse attn@v + concat + W_fuse
  m_k<<<dim3(128, 4, 3), 128, 0, stream>>>(W_fu, attb, bv, Mb, cb);
  weff_k<<<dim3(128, 4, 3), 128, 0, stream>>>(Mb, Wv, wefb);
  fuse_mfma_k<<<dim3(128, 2, 4), 256, 0, stream>>>(wefb, f0t, f1t, f2t, b_fu, cb, bufA, s_fuse);

  // ---- att_in = merged + silu(GN(fused_pre)); att_out = GN(att_in) -> NHWC bf16
  gn_silu_add_k<<<4096, 256, 0, stream>>>(bufA, s_fuse, gfug, gfub, bufB, s_gnout);
  gnout_nhwc_k<<<dim3(256, 4, 4), 256, 0, stream>>>(bufA, s_gnout, goug, goub, xbf);

  // ---- r1 = relu(BN(conv(att_out, W_r1)))
  conv3_k<128, 128, 64, 2, 4><<<dim3(128, 4, 2), 256, 0, stream>>>(xbf, wpk_r1, bufB, 128);
  bn_sums_k<<<dim3(128, 16), 256, 0, stream>>>(bufB, s_bn1, 128);
  bnrelu_nhwc_k<<<dim3(256, 4, 4), 256, 0, stream>>>(bufB, s_bn1, bn1g, bn1b, xbf);

  // ---- r2 = relu(BN(conv(r1, W_r2))) -> d_out
  conv3_k<128, 128, 64, 2, 4><<<dim3(128, 4, 2), 256, 0, stream>>>(xbf, wpk_r2, out, 128);
  bn_sums_k<<<dim3(128, 16), 256, 0, stream>>>(out, s_bn2, 128);
  bn_apply8_k<<<4096, 256, 0, stream>>>(out, s_bn2, bn2g, bn2b, nullptr, nullptr);
}

// Round 10
// 849.043 us; speedup vs baseline: 1.1114x; 1.1114x over previous
//
#include <hip/hip_runtime.h>
#include <math.h>

#define EPSV 1e-5f

typedef __attribute__((ext_vector_type(8))) short short8;
typedef __attribute__((ext_vector_type(4))) float f32x4;

__device__ inline unsigned short f2bf(float x) {
  unsigned int u = __float_as_uint(x);
  return (unsigned short)((u + 0x7FFFu + ((u >> 16) & 1u)) >> 16);
}
__device__ inline float bf2f(unsigned short v) {
  return __uint_as_float(((unsigned int)v) << 16);
}

// ============================================================================
// Pack all conv weights fp32 [Cout][Cin][3][3] -> bf16 [9][128][Cin], one launch
// ============================================================================
__global__ void packall_k(const float* __restrict__ W_up, const float* __restrict__ W_r1,
                          const float* __restrict__ W_r2, const float* __restrict__ W_ll,
                          const float* __restrict__ W_hi, unsigned short* __restrict__ p_up,
                          unsigned short* __restrict__ p_r1, unsigned short* __restrict__ p_r2,
                          unsigned short* __restrict__ p_dt) {
  int idx = blockIdx.x * 256 + threadIdx.x;
  const float* src; unsigned short* dst; int Cin, co_off, local;
  if (idx < 294912)       { src = W_up; dst = p_up; Cin = 256; co_off = 0;  local = idx; }
  else if (idx < 442368)  { src = W_r1; dst = p_r1; Cin = 128; co_off = 0;  local = idx - 294912; }
  else if (idx < 589824)  { src = W_r2; dst = p_r2; Cin = 128; co_off = 0;  local = idx - 442368; }
  else if (idx < 626688)  { src = W_ll; dst = p_dt; Cin = 128; co_off = 0;  local = idx - 589824; }
  else if (idx < 737280)  { src = W_hi; dst = p_dt; Cin = 128; co_off = 32; local = idx - 626688; }
  else return;
  int kk = local % 9;
  int ci = (local / 9) % Cin;
  int co = local / (9 * Cin);
  dst[((long)kk * 128 + co_off + co) * Cin + ci] = f2bf(src[local]);
}

// ============================================================================
// Tiled NCHW fp32 -> NHWC bf16 transpose/convert (+optional NCHW bf16 copy).
// ============================================================================
__global__ void t_nhwc_k(const float* __restrict__ in, unsigned short* __restrict__ out,
                         unsigned short* __restrict__ out_nchw, int C, int HW) {
  __shared__ unsigned short lds[64][34];
  int b = blockIdx.z;
  int c0 = blockIdx.y << 5;
  int hw0 = blockIdx.x << 6;
  int t = threadIdx.x;
  int c = t >> 3, j0 = (t & 7) << 3;
  long ibase = ((long)b * C + c0 + c) * HW + hw0 + j0;
  const float* p = in + ibase;
  int4 nv; unsigned short* ns = (unsigned short*)&nv;
#pragma unroll
  for (int j = 0; j < 8; j++) {
    unsigned short v = f2bf(p[j]);
    lds[j0 + j][c] = v;
    ns[j] = v;
  }
  if (out_nchw) *(int4*)(out_nchw + ibase) = nv;
  __syncthreads();
  int hw = t >> 2, k = (t & 3) << 3;
  unsigned short* q = out + ((long)(b * HW + hw0 + hw)) * C + c0 + k;
  int4 val;
  unsigned short* vs = (unsigned short*)&val;
#pragma unroll
  for (int i = 0; i < 8; i++) vs[i] = lds[hw][k + i];
  *(int4*)q = val;
}

// ============================================================================
// GN-apply fused with NHWC bf16 transpose (att_out -> conv r1 input)
// ============================================================================
__global__ void gnout_nhwc_k(const float* __restrict__ in, const float* __restrict__ sums,
                             const float* __restrict__ gamma, const float* __restrict__ beta,
                             unsigned short* __restrict__ out) {
  __shared__ unsigned short lds[64][34];
  int b = blockIdx.z;
  int c0 = blockIdx.y << 5;
  int hw0 = blockIdx.x << 6;
  int t = threadIdx.x;
  int c = t >> 3, j0 = (t & 7) << 3;
  int ch = c0 + c;
  int sidx = b * 8 + (ch >> 4);
  const float ic = 1.f / 262144.f;
  float m = sums[2 * sidx] * ic;
  float r = rsqrtf(fmaxf(sums[2 * sidx + 1] * ic - m * m, 0.f) + EPSV);
  float ga = gamma[ch] * r, be = beta[ch] - m * r * gamma[ch];
  const float* p = in + (((long)(b * 128 + ch)) << 14) + hw0 + j0;
#pragma unroll
  for (int j = 0; j < 8; j++) lds[j0 + j][c] = f2bf(p[j] * ga + be);
  __syncthreads();
  int hw = t >> 2, k = (t & 3) << 3;
  unsigned short* q = out + ((long)(b * 16384 + hw0 + hw)) * 128 + c0 + k;
  int4 val;
  unsigned short* vs = (unsigned short*)&val;
#pragma unroll
  for (int i = 0; i < 8; i++) vs[i] = lds[hw][k + i];
  *(int4*)q = val;
}

// BN+relu fused with NHWC bf16 transpose (r1 -> conv r2 input)
__global__ void bnrelu_nhwc_k(const float* __restrict__ in, const float* __restrict__ sums,
                              const float* __restrict__ gamma, const float* __restrict__ beta,
                              unsigned short* __restrict__ out) {
  __shared__ unsigned short lds[64][34];
  int b = blockIdx.z;
  int c0 = blockIdx.y << 5;
  int hw0 = blockIdx.x << 6;
  int t = threadIdx.x;
  int c = t >> 3, j0 = (t & 7) << 3;
  int ch = c0 + c;
  const float ic = 1.f / 65536.f;
  float m = sums[2 * ch] * ic;
  float r = rsqrtf(fmaxf(sums[2 * ch + 1] * ic - m * m, 0.f) + EPSV);
  float ga = gamma[ch] * r, be = beta[ch] - m * r * gamma[ch];
  const float* p = in + (((long)(b * 128 + ch)) << 14) + hw0 + j0;
#pragma unroll
  for (int j = 0; j < 8; j++) lds[j0 + j][c] = f2bf(fmaxf(p[j] * ga + be, 0.f));
  __syncthreads();
  int hw = t >> 2, k = (t & 3) << 3;
  unsigned short* q = out + ((long)(b * 16384 + hw0 + hw)) * 128 + c0 + k;
  int4 val;
  unsigned short* vs = (unsigned short*)&val;
#pragma unroll
  for (int i = 0; i < 8; i++) vs[i] = lds[hw][k + i];
  *(int4*)q = val;
}

// ============================================================================
// TILED bilinear resize (align-corners) fp32 NCHW 64x64 -> bf16 NHWC 128x128.
// ============================================================================
__global__ __launch_bounds__(256) void resize_t_k(const float* __restrict__ in,
                                                  unsigned short* __restrict__ out,
                                                  int C, float s) {
  __shared__ float rows[2][32][68];
  int ho = blockIdx.x, cb = blockIdx.y, b = blockIdx.z;
  int t = threadIdx.x;
  float ys = ho * s;
  int y0 = (int)ys; float wy = ys - y0;
  int y1 = min(y0 + 1, 63);
  for (int i = t; i < 1024; i += 256) {
    int r = i >> 9, c = (i >> 4) & 31, seg = i & 15;
    const float* p = in + (((long)(b * C + cb * 32 + c)) << 12) + ((r ? y1 : y0) << 6) + (seg << 2);
    *(float4*)&rows[r][c][seg << 2] = *(const float4*)p;
  }
  __syncthreads();
  int cs = t & 3;
#pragma unroll
  for (int half = 0; half < 2; half++) {
    int wo = (t >> 2) + half * 64;
    float xs = wo * s;
    int x0 = (int)xs; float wx = xs - x0;
    int x1 = min(x0 + 1, 63);
    int4 val; unsigned short* vs = (unsigned short*)&val;
#pragma unroll
    for (int j = 0; j < 8; j++) {
      int c = cs * 8 + j;
      float v00 = rows[0][c][x0], v01 = rows[0][c][x1];
      float v10 = rows[1][c][x0], v11 = rows[1][c][x1];
      float r0 = v00 + (v01 - v00) * wx;
      float r1 = v10 + (v11 - v10) * wx;
      vs[j] = f2bf(r0 + (r1 - r0) * wy);
    }
    *(int4*)(out + ((long)((b * 128 + ho) * 128 + wo)) * C + cb * 32 + cs * 8) = val;
  }
}

// Bilinear resize fp32 NCHW -> bf16 NCHW (skip_global feats copy), 8 wo/thread
__global__ void resize_nchwbf_k(const float* __restrict__ in, unsigned short* __restrict__ out,
                                float s) {
  long idx = (long)blockIdx.x * 256 + threadIdx.x;  // 1048576 total
  int seg = (int)(idx & 15); long t2 = idx >> 4;
  int ho = (int)(t2 & 127); t2 >>= 7;
  int c = (int)(t2 & 127); int b = (int)(t2 >> 7);
  float ys = ho * s;
  int y0 = (int)ys; float wy = ys - y0;
  int y1 = min(y0 + 1, 63);
  const float* p = in + (((long)(b * 128 + c)) << 12);
  int4 val; unsigned short* vs = (unsigned short*)&val;
#pragma unroll
  for (int j = 0; j < 8; j++) {
    int wo = seg * 8 + j;
    float xs = wo * s;
    int x0 = (int)xs; float wx = xs - x0;
    int x1 = min(x0 + 1, 63);
    float v00 = p[(y0 << 6) + x0], v01 = p[(y0 << 6) + x1];
    float v10 = p[(y1 << 6) + x0], v11 = p[(y1 << 6) + x1];
    float r0 = v00 + (v01 - v00) * wx;
    float r1 = v10 + (v11 - v10) * wx;
    vs[j] = f2bf(r0 + (r1 - r0) * wy);
  }
  *(int4*)(out + (((long)(b * 128 + c)) << 14) + (ho << 7) + seg * 8) = val;
}

// ============================================================================
// MFMA implicit-GEMM 3x3 conv, det-branch variant (R7 structure, COB split).
// ============================================================================
template <int W_, int CIN, int COB, int FC, int FN>
__global__ __launch_bounds__(256) void conv2_k(
    const unsigned short* __restrict__ xin, const unsigned short* __restrict__ wpk,
    float* __restrict__ out, int H) {
  constexpr int CP = 40;
  __shared__ unsigned short wbuf[3 * COB * CP];
  __shared__ unsigned short rbuf[(W_ + 2) * CP];
  int h = blockIdx.x, b = blockIdx.y, cb = blockIdx.z;
  int t = threadIdx.x;
  int wid = t >> 6, lane = t & 63;
  int co0 = (wid >> 1) * (FC * 16);
  int n0 = (wid & 1) * (FN * 16);
  int lm = lane & 15, lk = lane >> 4;
  f32x4 acc[FC][FN];
#pragma unroll
  for (int i = 0; i < FC; i++)
#pragma unroll
    for (int j = 0; j < FN; j++) acc[i][j] = (f32x4){0.f, 0.f, 0.f, 0.f};

  constexpr int WEL = 3 * COB * 32 / 8;
  constexpr int REL = (W_ + 2) * 32 / 8;

  for (int c0 = 0; c0 < CIN; c0 += 32) {
    for (int ky = 0; ky < 3; ky++) {
      int hr = h + ky - 1;
      __syncthreads();
      for (int i = t; i < WEL + REL; i += 256) {
        if (i < WEL) {
          int e = i * 8;
          int kx = e / (COB * 32);
          int rem = e - kx * (COB * 32);
          int co = rem >> 5, ci = rem & 31;
          const unsigned short* g =
              wpk + ((long)((ky * 3 + kx) * 128 + cb * COB + co)) * CIN + c0 + ci;
          *(int4*)&wbuf[(kx * COB + co) * CP + ci] = *(const int4*)g;
        } else {
          int e = (i - WEL) * 8;
          int col = e >> 5, ci = e & 31;
          int gc = col - 1;
          int4 v = {0, 0, 0, 0};
          if (hr >= 0 && hr < H && gc >= 0 && gc < W_)
            v = *(const int4*)(xin + ((long)((b * H + hr) * W_ + gc)) * CIN + c0 + ci);
          *(int4*)&rbuf[col * CP + ci] = v;
        }
      }
      __syncthreads();
#pragma unroll
      for (int kx = 0; kx < 3; kx++) {
        short8 afr[FC], bfr[FN];
#pragma unroll
        for (int i = 0; i < FC; i++)
          afr[i] = *(const short8*)&wbuf[(kx * COB + co0 + i * 16 + lm) * CP + lk * 8];
#pragma unroll
        for (int j = 0; j < FN; j++)
          bfr[j] = *(const short8*)&rbuf[(n0 + j * 16 + lm + kx) * CP + lk * 8];
#pragma unroll
        for (int i = 0; i < FC; i++)
#pragma unroll
          for (int j = 0; j < FN; j++)
            acc[i][j] = __builtin_amdgcn_mfma_f32_16x16x32_bf16(afr[i], bfr[j], acc[i][j], 0, 0, 0);
      }
    }
  }
#pragma unroll
  for (int i = 0; i < FC; i++) {
#pragma unroll
    for (int r = 0; r < 4; r++) {
      int col = cb * COB + co0 + i * 16 + lk * 4 + r;
      long obase = (((long)(b * 128 + col)) * H + h) * W_;
#pragma unroll
      for (int j = 0; j < FN; j++)
        out[obase + n0 + j * 16 + lm] = acc[i][j][r];
    }
  }
}

// ============================================================================
// conv4 (R10): conv2 + ping-pong LDS + register prefetch. Per phase: issue
// next phase's global loads into regs BEFORE the MFMA burst, write them to the
// other LDS buffer after (vmcnt drain overlaps MFMA), ONE barrier per phase.
// Same COB=64 tiling / weight-through-LDS path as R7 (proven best fetch
// behavior). LDS 2x25.8KB, grid (H, B, 2).
// ============================================================================
template <int W_, int CIN, int COB, int FC, int FN>
__global__ __launch_bounds__(256) void conv4_k(
    const unsigned short* __restrict__ xin, const unsigned short* __restrict__ wpk,
    float* __restrict__ out, int H) {
  constexpr int CP = 40;
  constexpr int WROWS = 3 * COB;
  constexpr int RROWS = W_ + 2;
  constexpr int BUF = (WROWS + RROWS) * CP;
  __shared__ unsigned short sbuf[2][BUF];
  constexpr int WEL = WROWS * 32 / 8;
  constexpr int REL = RROWS * 32 / 8;
  constexpr int TOT = WEL + REL;
  constexpr int NLD = (TOT + 255) / 256;
  constexpr int NPH = (CIN / 32) * 3;

  int h = blockIdx.x, b = blockIdx.y, cb = blockIdx.z;
  int t = threadIdx.x;
  int wid = t >> 6, lane = t & 63;
  int co0 = (wid >> 1) * (FC * 16);
  int n0 = (wid & 1) * (FN * 16);
  int lm = lane & 15, lk = lane >> 4;
  f32x4 acc[FC][FN];
#pragma unroll
  for (int i = 0; i < FC; i++)
#pragma unroll
    for (int j = 0; j < FN; j++) acc[i][j] = (f32x4){0.f, 0.f, 0.f, 0.f};

  int4 v[NLD]; int dst[NLD];
  auto load_phase = [&](int ph) {
    int c3 = ph / 3;
    int ky = ph - c3 * 3;
    int c0 = c3 << 5;
    int hr = h + ky - 1;
#pragma unroll
    for (int k = 0; k < NLD; k++) {
      int i = t + k * 256;
      int4 val = {0, 0, 0, 0};
      int d = -1;
      if (i < WEL) {
        int e = i * 8;
        int kx = e / (COB * 32);
        int rem = e - kx * (COB * 32);
        int co = rem >> 5, ci = rem & 31;
        val = *(const int4*)(wpk + ((long)((ky * 3 + kx) * 128 + cb * COB + co)) * CIN + c0 + ci);
        d = (kx * COB + co) * CP + ci;
      } else if (i < TOT) {
        int e = (i - WEL) * 8;
        int col = e >> 5, ci = e & 31;
        int gc = col - 1;
        if (hr >= 0 && hr < H && gc >= 0 && gc < W_)
          val = *(const int4*)(xin + ((long)((b * H + hr) * W_ + gc)) * CIN + c0 + ci);
        d = (WROWS + col) * CP + ci;
      }
      v[k] = val; dst[k] = d;
    }
  };
  auto store_phase = [&](int buf) {
#pragma unroll
    for (int k = 0; k < NLD; k++)
      if (dst[k] >= 0) *(int4*)&sbuf[buf][dst[k]] = v[k];
  };

  load_phase(0);
  store_phase(0);
  __syncthreads();
  for (int p = 0; p < NPH; p++) {
    if (p + 1 < NPH) load_phase(p + 1);
    const unsigned short* cw = sbuf[p & 1];
    const unsigned short* cr = sbuf[p & 1] + WROWS * CP;
#pragma unroll
    for (int kx = 0; kx < 3; kx++) {
      short8 afr[FC], bfr[FN];
#pragma unroll
      for (int i = 0; i < FC; i++)
        afr[i] = *(const short8*)&cw[(kx * COB + co0 + i * 16 + lm) * CP + lk * 8];
#pragma unroll
      for (int j = 0; j < FN; j++)
        bfr[j] = *(const short8*)&cr[(n0 + j * 16 + lm + kx) * CP + lk * 8];
#pragma unroll
      for (int i = 0; i < FC; i++)
#pragma unroll
        for (int j = 0; j < FN; j++)
          acc[i][j] = __builtin_amdgcn_mfma_f32_16x16x32_bf16(afr[i], bfr[j], acc[i][j], 0, 0, 0);
    }
    if (p + 1 < NPH) store_phase((p + 1) & 1);
    __syncthreads();
  }
#pragma unroll
  for (int i = 0; i < FC; i++) {
#pragma unroll
    for (int r = 0; r < 4; r++) {
      int col = cb * COB + co0 + i * 16 + lk * 4 + r;
      long obase = (((long)(b * 128 + col)) * H + h) * W_;
#pragma unroll
      for (int j = 0; j < FN; j++)
        out[obase + n0 + j * 16 + lm] = acc[i][j][r];
    }
  }
}

// ============================================================================
// stats reductions (BW-bound, 1-2 atomics per BLOCK)
// ============================================================================
__global__ void gn_sums_k(const float* __restrict__ x, float* __restrict__ sums,
                          int Ctot, int coff, int cpg, int HW, int goff) {
  int bg = blockIdx.x; int b = bg >> 3, g = bg & 7;
  const float* p = x + ((long)b * Ctot + coff + (long)g * cpg) * HW;
  long len = (long)cpg * HW;
  long chunk = len / gridDim.y;
  long s = (long)blockIdx.y * chunk, e = s + chunk;
  float s0 = 0.f, s1 = 0.f;
  for (long i = s + threadIdx.x; i < e; i += 256) {
    float v = p[i]; s0 += v; s1 += v * v;
  }
  __shared__ float r0[256], r1[256];
  int t = threadIdx.x;
  r0[t] = s0; r1[t] = s1;
  __syncthreads();
  for (int off = 128; off > 0; off >>= 1) {
    if (t < off) { r0[t] += r0[t + off]; r1[t] += r1[t + off]; }
    __syncthreads();
  }
  if (t == 0) {
    int gi = b * 16 + goff + g;
    atomicAdd(&sums[2 * gi], r0[0]);
    atomicAdd(&sums[2 * gi + 1], r1[0]);
  }
}

__global__ void bn_sums_k(const float* __restrict__ x, float* __restrict__ sums, int C) {
  int c = blockIdx.x;
  long total = 4L << 14;
  long chunk = total / gridDim.y;
  long s = (long)blockIdx.y * chunk, e = s + chunk;
  float s0 = 0.f, s1 = 0.f;
  for (long i = s + threadIdx.x; i < e; i += 256) {
    int b = (int)(i >> 14); int hw = (int)(i & 16383);
    float v = x[(((long)b * C + c) << 14) + hw];
    s0 += v; s1 += v * v;
  }
  __shared__ float r0[256], r1[256];
  int t = threadIdx.x;
  r0[t] = s0; r1[t] = s1;
  __syncthreads();
  for (int off = 128; off > 0; off >>= 1) {
    if (t < off) { r0[t] += r0[t + off]; r1[t] += r1[t + off]; }
    __syncthreads();
  }
  if (t == 0) { atomicAdd(&sums[2 * c], r0[0]); atomicAdd(&sums[2 * c + 1], r1[0]); }
}

// ============================================================================
// IDWT(haar) fused with GN+tanh+scale; stats finalized inline from s_det
// ============================================================================
__global__ void idwt_k(const float* __restrict__ det, const float* __restrict__ sd,
                       const float* __restrict__ gll, const float* __restrict__ bll,
                       const float* __restrict__ ghi, const float* __restrict__ bhi,
                       const float* __restrict__ wsc, float* __restrict__ rec) {
  long idx = ((long)blockIdx.x << 8) + threadIdx.x;
  if (idx >= (long)4 * 32 * 64 * 64) return;
  int j = (int)(idx & 63); long t = idx >> 6;
  int i = (int)(t & 63); t >>= 6;
  int c = (int)(t & 31); int b = (int)(t >> 5);
  float s = wsc[0]; s = fminf(fmaxf(s, 1.f), 5.f);
  const float icll = 1.f / 16384.f, ichi = 1.f / 49152.f;
  const float* dp = det + ((long)b << 19);
  long sp = ((long)i << 6) + j;
  int gi = b * 16 + (c >> 2);
  float m = sd[2 * gi] * icll;
  float r = rsqrtf(fmaxf(sd[2 * gi + 1] * icll - m * m, 0.f) + EPSV);
  float ll = tanhf((dp[((long)c << 12) + sp] - m) * r * gll[c] + bll[c]) * s;
  int hc = c; gi = b * 16 + 8 + hc / 12;
  m = sd[2 * gi] * ichi; r = rsqrtf(fmaxf(sd[2 * gi + 1] * ichi - m * m, 0.f) + EPSV);
  float lh = tanhf((dp[((long)(32 + hc) << 12) + sp] - m) * r * ghi[hc] + bhi[hc]) * s;
  hc = 32 + c; gi = b * 16 + 8 + hc / 12;
  m = sd[2 * gi] * ichi; r = rsqrtf(fmaxf(sd[2 * gi + 1] * ichi - m * m, 0.f) + EPSV);
  float hl = tanhf((dp[((long)(32 + hc) << 12) + sp] - m) * r * ghi[hc] + bhi[hc]) * s;
  hc = 64 + c; gi = b * 16 + 8 + hc / 12;
  m = sd[2 * gi] * ichi; r = rsqrtf(fmaxf(sd[2 * gi + 1] * ichi - m * m, 0.f) + EPSV);
  float hh = tanhf((dp[((long)(32 + hc) << 12) + sp] - m) * r * ghi[hc] + bhi[hc]) * s;
  float x00 = (ll + lh + hl + hh) * 0.5f;
  float x01 = (ll - lh + hl - hh) * 0.5f;
  float x10 = (ll + lh - hl - hh) * 0.5f;
  float x11 = (ll - lh - hl + hh) * 0.5f;
  float* rp = rec + (((long)b * 32 + c) << 14) + ((long)i << 8) + (j << 1);
  rp[0] = x00; rp[1] = x01; rp[128] = x10; rp[129] = x11;
}

// ============================================================================
// skip_up_raw = W_adj (128x32) @ rec; fused GN-sums accumulation
// ============================================================================
__global__ __launch_bounds__(256) void adj_k(const float* __restrict__ rec,
                                             const float* __restrict__ Wadj,
                                             float* __restrict__ out,
                                             float* __restrict__ gsums) {
  __shared__ float ls[32][256];
  int n0 = blockIdx.x << 8;
  int o0 = blockIdx.y << 4;
  int b = blockIdx.z;
  int t = threadIdx.x;
  for (int idx = t; idx < 32 * 256; idx += 256) {
    int c = idx >> 8, n = idx & 255;
    ls[c][n] = rec[(((long)b * 32 + c) << 14) + n0 + n];
  }
  __syncthreads();
  float acc[16];
#pragma unroll
  for (int i = 0; i < 16; i++) acc[i] = 0.f;
  for (int c = 0; c < 32; c++) {
    float v = ls[c][t];
#pragma unroll
    for (int i = 0; i < 16; i++) acc[i] += v * Wadj[(o0 + i) * 32 + c];
  }
  float s0 = 0.f, s1 = 0.f;
#pragma unroll
  for (int i = 0; i < 16; i++) {
    out[(((long)b * 128 + o0 + i) << 14) + n0 + t] = acc[i];
    s0 += acc[i]; s1 += acc[i] * acc[i];
  }
  __syncthreads();
  float* red = (float*)ls;
  red[t] = s0; red[256 + t] = s1;
  __syncthreads();
  for (int off = 128; off > 0; off >>= 1) {
    if (t < off) { red[t] += red[t + off]; red[256 + t] += red[256 + t + off]; }
    __syncthreads();
  }
  if (t == 0) {
    int gi = b * 8 + (o0 >> 4);
    atomicAdd(&gsums[2 * gi], red[0]);
    atomicAdd(&gsums[2 * gi + 1], red[256]);
  }
}

// ============================================================================
// GN relu apply (skip_up), vectorized 8/thread, stats inline from sums
// ============================================================================
__global__ void gn_relu_k(float* __restrict__ x, const float* __restrict__ sums,
                          const float* __restrict__ gamma, const float* __restrict__ beta) {
  long i0 = ((long)blockIdx.x * 256 + threadIdx.x) * 8;
  int ch = (int)((i0 >> 14) & 127);
  int b = (int)(i0 >> 21);
  int sidx = b * 8 + (ch >> 4);
  const float ic = 1.f / 262144.f;
  float m = sums[2 * sidx] * ic;
  float r = rsqrtf(fmaxf(sums[2 * sidx + 1] * ic - m * m, 0.f) + EPSV);
  float ga = gamma[ch] * r, be = beta[ch] - m * r * gamma[ch];
#pragma unroll
  for (int j = 0; j < 8; j++) {
    float v = fmaxf(x[i0 + j] * ga + be, 0.f);
    x[i0 + j] = v;
  }
}

// BN relu apply (+add +bf16 NCHW copy), 8/thread
__global__ void bn_apply8_k(float* __restrict__ x, const float* __restrict__ sums,
                            const float* __restrict__ gamma, const float* __restrict__ beta,
                            const float* __restrict__ add, unsigned short* __restrict__ obf) {
  long i0 = ((long)blockIdx.x * 256 + threadIdx.x) * 8;
  int ch = (int)((i0 >> 14) & 127);
  const float ic = 1.f / 65536.f;
  float m = sums[2 * ch] * ic;
  float r = rsqrtf(fmaxf(sums[2 * ch + 1] * ic - m * m, 0.f) + EPSV);
  float ga = gamma[ch] * r, be = beta[ch] - m * r * gamma[ch];
  int4 ov; unsigned short* os = (unsigned short*)&ov;
#pragma unroll
  for (int j = 0; j < 8; j++) {
    float v = fmaxf(x[i0 + j] * ga + be, 0.f);
    if (add) v += add[i0 + j];
    x[i0 + j] = v;
    os[j] = f2bf(v);
  }
  if (obf) *(int4*)(obf + i0) = ov;
}

// GN silu apply + add merged (att_in), accumulate next-GN sums. 8/thread.
__global__ void gn_silu_add_k(float* __restrict__ x, const float* __restrict__ sums,
                              const float* __restrict__ gamma, const float* __restrict__ beta,
                              const float* __restrict__ add, float* __restrict__ osums) {
  long i0 = ((long)blockIdx.x * 256 + threadIdx.x) * 8;
  int ch = (int)((i0 >> 14) & 127);
  int b = (int)(i0 >> 21);
  int sidx = b * 8 + (ch >> 4);
  const float ic = 1.f / 262144.f;
  float m = sums[2 * sidx] * ic;
  float r = rsqrtf(fmaxf(sums[2 * sidx + 1] * ic - m * m, 0.f) + EPSV);
  float ga = gamma[ch] * r, be = beta[ch] - m * r * gamma[ch];
  float s0 = 0.f, s1 = 0.f;
#pragma unroll
  for (int j = 0; j < 8; j++) {
    float v = x[i0 + j] * ga + be;
    v = v / (1.f + expf(-v));
    v += add[i0 + j];
    x[i0 + j] = v;
    s0 += v; s1 += v * v;
  }
  __shared__ float r0[256], r1[256];
  int t = threadIdx.x;
  r0[t] = s0; r1[t] = s1;
  __syncthreads();
  for (int off = 128; off > 0; off >>= 1) {
    if (t < off) { r0[t] += r0[t + off]; r1[t] += r1[t + off]; }
    __syncthreads();
  }
  if (t == 0) {
    atomicAdd(&osums[2 * sidx], r0[0]);
    atomicAdd(&osums[2 * sidx + 1], r1[0]);
  }
}

// ============================================================================
// colsum of 4 bf16-NCHW buffers -> Sall[2048]
// ============================================================================
__global__ void colsum4_k(const unsigned short* __restrict__ m, const unsigned short* __restrict__ f0,
                          const unsigned short* __restrict__ f1, const unsigned short* __restrict__ f2,
                          float* __restrict__ S) {
  int bc = blockIdx.x, which = blockIdx.y;
  const unsigned short* p = (which == 0 ? m : which == 1 ? f0 : which == 2 ? f1 : f2) + ((long)bc << 14);
  float a = 0.f;
  for (int i = threadIdx.x; i < 2048; i += 256) {
    int4 v = *(const int4*)(p + i * 8);
    unsigned short* vs = (unsigned short*)&v;
#pragma unroll
    for (int j = 0; j < 8; j++) a += bf2f(vs[j]);
  }
  __shared__ float red[256];
  red[threadIdx.x] = a;
  __syncthreads();
  for (int off = 128; off > 0; off >>= 1) {
    if (threadIdx.x < off) red[threadIdx.x] += red[threadIdx.x + off];
    __syncthreads();
  }
  if (threadIdx.x == 0) S[which * 512 + bc] = red[0];
}

// ============================================================================
// Gram via MFMA: Gpart[nc][p*4+b][c][c'] partial over 512-n chunk.
// ============================================================================
__global__ __launch_bounds__(256) void gram_mfma_k(
    const unsigned short* __restrict__ mbf, const unsigned short* __restrict__ f0,
    const unsigned short* __restrict__ f1, const unsigned short* __restrict__ f2,
    float* __restrict__ Gpart) {
  constexpr int CP = 40;
  __shared__ unsigned short As[128 * CP], Bs[128 * CP];
  int nc = blockIdx.x, p = blockIdx.y, b = blockIdx.z;
  const unsigned short* fp = (p == 0 ? f0 : p == 1 ? f1 : f2);
  const unsigned short* ma = mbf + ((long)b << 21);
  const unsigned short* fa = fp + ((long)b << 21);
  int t = threadIdx.x;
  int wid = t >> 6, lane = t & 63;
  int c0 = (wid >> 1) << 6;
  int cp0 = (wid & 1) << 6;
  int lm = lane & 15, lk = lane >> 4;
  f32x4 acc[4][4];
#pragma unroll
  for (int i = 0; i < 4; i++)
#pragma unroll
    for (int j = 0; j < 4; j++) acc[i][j] = (f32x4){0.f, 0.f, 0.f, 0.f};
  for (int ks = 0; ks < 16; ks++) {
    int n = (nc << 9) + (ks << 5);
    __syncthreads();
#pragma unroll
    for (int i = 0; i < 2; i++) {
      int idx = t + (i << 8);
      int row = idx >> 2, q = idx & 3;
      *(int4*)&As[row * CP + q * 8] = *(const int4*)(ma + ((long)row << 14) + n + q * 8);
      *(int4*)&Bs[row * CP + q * 8] = *(const int4*)(fa + ((long)row << 14) + n + q * 8);
    }
    __syncthreads();
    short8 af[4], bfr[4];
#pragma unroll
    for (int i = 0; i < 4; i++) af[i] = *(const short8*)&As[(c0 + i * 16 + lm) * CP + lk * 8];
#pragma unroll
    for (int j = 0; j < 4; j++) bfr[j] = *(const short8*)&Bs[(cp0 + j * 16 + lm) * CP + lk * 8];
#pragma unroll
    for (int i = 0; i < 4; i++)
#pragma unroll
      for (int j = 0; j < 4; j++)
        acc[i][j] = __builtin_amdgcn_mfma_f32_16x16x32_bf16(af[i], bfr[j], acc[i][j], 0, 0, 0);
  }
  float* Gp = Gpart + (((long)(nc * 12 + p * 4 + b)) << 14);
#pragma unroll
  for (int i = 0; i < 4; i++)
#pragma unroll
    for (int j = 0; j < 4; j++) {
      int cp = cp0 + j * 16 + lm;
#pragma unroll
      for (int r = 0; r < 4; r++) {
        int c = c0 + i * 16 + lk * 4 + r;
        Gp[c * 128 + cp] = acc[i][j][r];
      }
    }
}

// reduce 32 partials -> G
__global__ void gred_k(const float* __restrict__ Gpart, float* __restrict__ G) {
  int cell = blockIdx.x * 256 + threadIdx.x;  // 196608
  int pb = cell >> 14, rem = cell & 16383;
  float a = 0.f;
  for (int nc = 0; nc < 32; nc++) a += Gpart[(((long)(nc * 12 + pb)) << 14) + rem];
  G[cell] = a;
}

// ============================================================================
// attention logits from Gram + softmax
// ============================================================================
__global__ __launch_bounds__(256) void attn_k(const float* __restrict__ G,
                                              const float* __restrict__ Sall,
                                              const float* __restrict__ Wq,
                                              const float* __restrict__ bq,
                                              const float* __restrict__ Wk,
                                              const float* __restrict__ bk,
                                              float* __restrict__ attn) {
  int h = blockIdx.x, b = blockIdx.y, p = blockIdx.z;
  __shared__ float T[32][129];
  __shared__ float QS2[32], KS1[32];
  __shared__ float L[32][33];
  const float* S2 = Sall;
  const float* S1 = Sall + 512;
  const float* Gpb = G + ((long)(p * 4 + b) << 14);
  const float* Wqp = Wq + p * 16384;
  const float* Wkp = Wk + p * 16384;
  int t = threadIdx.x;
  if (t < 32) {
    float a = 0.f;
    for (int c = 0; c < 128; c++) a += Wqp[(h * 32 + t) * 128 + c] * S2[b * 128 + c];
    QS2[t] = a;
  } else if (t < 64) {
    int e = t - 32;
    float a = 0.f;
    for (int c = 0; c < 128; c++) a += Wkp[(h * 32 + e) * 128 + c] * S1[(p * 4 + b) * 128 + c];
    KS1[e] = a;
  }
  __syncthreads();
  for (int ii = t; ii < 4096; ii += 256) {
    int d = ii >> 7, cp = ii & 127;
    float a = 0.f;
    for (int c = 0; c < 128; c++) a += Wqp[(h * 32 + d) * 128 + c] * Gpb[c * 128 + cp];
    T[d][cp] = a;
  }
  __syncthreads();
  const float scale = 0.17677669529663687f;
  for (int ii = t; ii < 1024; ii += 256) {
    int d = ii >> 5, e = ii & 31;
    float a = 0.f;
    for (int cp = 0; cp < 128; cp++) a += T[d][cp] * Wkp[(h * 32 + e) * 128 + cp];
    float bqv = bq[p * 128 + h * 32 + d], bkv = bk[p * 128 + h * 32 + e];
    a += bqv * KS1[e] + bkv * QS2[d] + 16384.f * bqv * bkv;
    L[d][e] = a * scale;
  }
  __syncthreads();
  if (t < 32) {
    float mx = -1e30f;
    for (int e = 0; e < 32; e++) mx = fmaxf(mx, L[t][e]);
    float sum = 0.f;
    for (int e = 0; e < 32; e++) { float ev = expf(L[t][e] - mx); L[t][e] = ev; sum += ev; }
    float inv = 1.f / sum;
    float* ap = attn + ((((long)(p * 4 + b)) * 4 + h) * 32 + t) * 32;
    for (int e = 0; e < 32; e++) ap[e] = L[t][e] * inv;
  }
}

// ============================================================================
// M + cbias
// ============================================================================
__global__ void m_k(const float* __restrict__ Wf, const float* __restrict__ attn,
                    const float* __restrict__ bv, float* __restrict__ M,
                    float* __restrict__ cbias) {
  int o = blockIdx.x, b = blockIdx.y, p = blockIdx.z;
  int ap = threadIdx.x;
  int h = ap >> 5;
  const float* at = attn + (((long)(p * 4 + b)) * 4 + h) * 1024;
  const float* wrow = Wf + o * 384 + p * 128 + h * 32;
  int e = ap & 31;
  float acc = 0.f;
  for (int d = 0; d < 32; d++) acc += wrow[d] * at[d * 32 + e];
  M[(((long)(p * 4 + b)) * 128 + o) * 128 + ap] = acc;
  __shared__ float red[128];
  red[ap] = acc * bv[p * 128 + ap];
  __syncthreads();
  for (int off = 64; off > 0; off >>= 1) {
    if (ap < off) red[ap] += red[ap + off];
    __syncthreads();
  }
  if (ap == 0) atomicAdd(&cbias[b * 128 + o], red[0]);
}

// Weff bf16: [b][o][384] with k = p*128+c
__global__ void weff_k(const float* __restrict__ M, const float* __restrict__ Wv,
                       unsigned short* __restrict__ Weff) {
  int o = blockIdx.x, b = blockIdx.y, p = blockIdx.z, c = threadIdx.x;
  const float* mrow = M + (((long)(p * 4 + b)) * 128 + o) * 128;
  const float* wv = Wv + p * 16384;
  float acc = 0.f;
  for (int a = 0; a < 128; a++) acc += mrow[a] * wv[a * 128 + c];
  Weff[((long)(b * 128 + o)) * 384 + p * 128 + c] = f2bf(acc);
}

// ============================================================================
// fused_pre = Weff @ feats, B from NHWC bf16 (straight int4 staging).
// ============================================================================
__global__ __launch_bounds__(256) void fuse_mfma_k(
    const unsigned short* __restrict__ Wef, const unsigned short* __restrict__ f0t,
    const unsigned short* __restrict__ f1t, const unsigned short* __restrict__ f2t,
    const float* __restrict__ bf_, const float* __restrict__ cbias,
    float* __restrict__ out, float* __restrict__ gsums) {
  constexpr int CP = 40;
  __shared__ unsigned short As[64 * CP], Bs[128 * CP];
  __shared__ float sred[8];
  int nc = blockIdx.x, ob = blockIdx.y, b = blockIdx.z;
  int t = threadIdx.x;
  int wid = t >> 6, lane = t & 63;
  int o0 = (wid >> 1) * 32;
  int n0 = (wid & 1) * 64;
  int lm = lane & 15, lk = lane >> 4;
  if (t < 8) sred[t] = 0.f;
  f32x4 acc[2][4];
#pragma unroll
  for (int i = 0; i < 2; i++)
#pragma unroll
    for (int j = 0; j < 4; j++) acc[i][j] = (f32x4){0.f, 0.f, 0.f, 0.f};
  for (int kp = 0; kp < 12; kp++) {
    int k0 = kp << 5;
    int p = k0 >> 7, cc0 = k0 & 127;
    const unsigned short* ft = (p == 0 ? f0t : p == 1 ? f1t : f2t);
    __syncthreads();
    for (int i = t; i < 768; i += 256) {
      if (i < 256) {
        int row = i >> 2, q = i & 3;
        *(int4*)&As[row * CP + q * 8] =
            *(const int4*)(Wef + ((long)(b * 128 + ob * 64 + row)) * 384 + k0 + q * 8);
      } else {
        int j2 = i - 256;
        int n = j2 >> 2, q = j2 & 3;
        *(int4*)&Bs[n * CP + q * 8] =
            *(const int4*)(ft + ((long)(b * 16384 + nc * 128 + n)) * 128 + cc0 + q * 8);
      }
    }
    __syncthreads();
    short8 af[2], bfr[4];
#pragma unroll
    for (int i = 0; i < 2; i++) af[i] = *(const short8*)&As[(o0 + i * 16 + lm) * CP + lk * 8];
#pragma unroll
    for (int j = 0; j < 4; j++) bfr[j] = *(const short8*)&Bs[(n0 + j * 16 + lm) * CP + lk * 8];
#pragma unroll
    for (int i = 0; i < 2; i++)
#pragma unroll
      for (int j = 0; j < 4; j++)
        acc[i][j] = __builtin_amdgcn_mfma_f32_16x16x32_bf16(af[i], bfr[j], acc[i][j], 0, 0, 0);
  }
#pragma unroll
  for (int i = 0; i < 2; i++) {
    float s0 = 0.f, s1 = 0.f;
#pragma unroll
    for (int r = 0; r < 4; r++) {
      int o = ob * 64 + o0 + i * 16 + lk * 4 + r;
      float bias = bf_[o] + cbias[b * 128 + o];
#pragma unroll
      for (int j = 0; j < 4; j++) {
        int n = (nc << 7) + n0 + j * 16 + lm;
        float v = acc[i][j][r] + bias;
        out[(((long)(b * 128 + o)) << 14) + n] = v;
        s0 += v; s1 += v * v;
      }
    }
#pragma unroll
    for (int off = 1; off < 64; off <<= 1) {
      s0 += __shfl_xor(s0, off, 64);
      s1 += __shfl_xor(s1, off, 64);
    }
    if (lane == 0) {
      int gl = (o0 >> 4) + i;  // 0..3
      atomicAdd(&sred[2 * gl], s0);
      atomicAdd(&sred[2 * gl + 1], s1);
    }
  }
  __syncthreads();
  if (t < 8) {
    int g = b * 8 + ob * 4 + (t >> 1);
    atomicAdd(&gsums[2 * g + (t & 1)], sred[t]);
  }
}

// ============================================================================
extern "C" void kernel_launch(void* const* d_in, const int* in_sizes, int n_in,
                              void* d_out, int out_size, void* d_ws, size_t ws_size,
                              hipStream_t stream) {
  const float* x      = (const float*)d_in[0];
  const float* sdet   = (const float*)d_in[1];
  const float* sstru  = (const float*)d_in[2];
  const float* sglob  = (const float*)d_in[3];
  const float* W_up   = (const float*)d_in[4];
  const float* bnug   = (const float*)d_in[5];
  const float* bnub   = (const float*)d_in[6];
  const float* W_ll   = (const float*)d_in[7];
  const float* gllg   = (const float*)d_in[8];
  const float* gllb   = (const float*)d_in[9];
  const float* W_hi   = (const float*)d_in[10];
  const float* ghig   = (const float*)d_in[11];
  const float* ghib   = (const float*)d_in[12];
  const float* wsc    = (const float*)d_in[13];
  const float* W_adj  = (const float*)d_in[14];
  const float* gadjg  = (const float*)d_in[15];
  const float* gadjb  = (const float*)d_in[16];
  const float* Wq     = (const float*)d_in[17];
  const float* bq     = (const float*)d_in[18];
  const float* Wk     = (const float*)d_in[19];
  const float* bk     = (const float*)d_in[20];
  const float* Wv     = (const float*)d_in[21];
  const float* bv     = (const float*)d_in[22];
  const float* W_fu   = (const float*)d_in[23];
  const float* b_fu   = (const float*)d_in[24];
  const float* gfug   = (const float*)d_in[25];
  const float* gfub   = (const float*)d_in[26];
  const float* goug   = (const float*)d_in[27];
  const float* goub   = (const float*)d_in[28];
  const float* W_r1   = (const float*)d_in[29];
  const float* bn1g   = (const float*)d_in[30];
  const float* bn1b   = (const float*)d_in[31];
  const float* W_r2   = (const float*)d_in[32];
  const float* bn2g   = (const float*)d_in[33];
  const float* bn2b   = (const float*)d_in[34];
  float* out = (float*)d_out;

  float* ws = (float*)d_ws;
  size_t off = 0;
  auto alloc = [&](size_t n) { float* p = ws + off; off += n; return p; };
  float* bufA = alloc(8388608);   // det+rec early; Gpart mid; fused_pre/att_in late
  float* det  = bufA;             // (4,128,64,64)
  float* rec  = bufA + 2097152;   // (4,32,128,128)
  float* Gpart = bufA;            // 32 x 12 x 16384 = 6.29M (after rec dead)
  float* bufB = alloc(8388608);   // conv_up out -> merged; later r1
  float* bufC = alloc(8388608);   // skip_up fp32; later f1t+f2t (bf16)
  unsigned short* f1t = (unsigned short*)bufC;            // NHWC bf16 sstru
  unsigned short* f2t = (unsigned short*)bufC + 8388608;  // NHWC bf16 glob
  unsigned short* xbf = (unsigned short*)alloc(8388608);  // NHWC bf16 conv inputs
  unsigned short* f0t = (unsigned short*)alloc(4194304);  // NHWC bf16 skip_up
  unsigned short* mbf = (unsigned short*)alloc(4194304);  // merged bf16 NCHW
  unsigned short* f0  = (unsigned short*)alloc(4194304);  // skip_up bf16 NCHW
  unsigned short* f1  = (unsigned short*)alloc(4194304);  // sstru bf16 NCHW
  unsigned short* f2  = (unsigned short*)alloc(4194304);  // glob-resized bf16 NCHW
  float* Gm   = alloc(196608);
  unsigned short* wpk_up = (unsigned short*)alloc(147456);
  unsigned short* wpk_r1 = (unsigned short*)alloc(73728);
  unsigned short* wpk_r2 = (unsigned short*)alloc(73728);
  unsigned short* wpk_dt = (unsigned short*)alloc(36864);
  unsigned short* wefb   = (unsigned short*)alloc(98304);
  float* Sall = alloc(2048);
  float* attb = alloc(49152);
  float* Mb   = alloc(196608);
  float* zr = alloc(1600);
  float* cb      = zr;            // 512
  float* s_det   = zr + 512;      // 128
  float* s_adj   = zr + 640;      // 64
  float* s_bnup  = zr + 704;      // 256
  float* s_fuse  = zr + 960;      // 64
  float* s_gnout = zr + 1024;     // 64
  float* s_bn1   = zr + 1088;     // 256
  float* s_bn2   = zr + 1344;     // 256

  const float s63 = 63.f / 127.f;

  hipMemsetAsync(zr, 0, 1600 * sizeof(float), stream);
  packall_k<<<2880, 256, 0, stream>>>(W_up, W_r1, W_r2, W_ll, W_hi,
                                      wpk_up, wpk_r1, wpk_r2, wpk_dt);

  // ---- detail branch
  t_nhwc_k<<<dim3(64, 4, 4), 256, 0, stream>>>(sdet, xbf, nullptr, 128, 4096);
  conv2_k<64, 128, 32, 1, 2><<<dim3(64, 4, 4), 256, 0, stream>>>(xbf, wpk_dt, det, 64);
  gn_sums_k<<<dim3(32, 4), 256, 0, stream>>>(det, s_det, 128, 0, 4, 4096, 0);
  gn_sums_k<<<dim3(32, 8), 256, 0, stream>>>(det, s_det, 128, 32, 12, 4096, 8);
  idwt_k<<<2048, 256, 0, stream>>>(det, s_det, gllg, gllb, ghig, ghib, wsc, rec);

  // ---- skip_up = relu(GN(W_adj @ rec))
  adj_k<<<dim3(64, 8, 4), 256, 0, stream>>>(rec, W_adj, bufC, s_adj);
  gn_relu_k<<<4096, 256, 0, stream>>>(bufC, s_adj, gadjg, gadjb);

  // ---- merged = relu(BN(conv_up(resize(x)))) + skip_up
  resize_t_k<<<dim3(128, 8, 4), 256, 0, stream>>>(x, xbf, 256, s63);
  conv4_k<128, 256, 64, 2, 4><<<dim3(128, 4, 2), 256, 0, stream>>>(xbf, wpk_up, bufB, 128);
  bn_sums_k<<<dim3(128, 16), 256, 0, stream>>>(bufB, s_bnup, 128);
  bn_apply8_k<<<4096, 256, 0, stream>>>(bufB, s_bnup, bnug, bnub, bufC, mbf);

  // ---- feats bf16 copies (NCHW for gram + NHWC for fuse, dual-write)
  t_nhwc_k<<<dim3(256, 4, 4), 256, 0, stream>>>(bufC, f0t, f0, 128, 16384);
  t_nhwc_k<<<dim3(256, 4, 4), 256, 0, stream>>>(sstru, f1t, f1, 128, 16384);
  resize_nchwbf_k<<<4096, 256, 0, stream>>>(sglob, f2, s63);
  resize_t_k<<<dim3(128, 4, 4), 256, 0, stream>>>(sglob, f2t, 128, s63);

  // ---- attention via Gram matrices (MFMA)
  colsum4_k<<<dim3(512, 4), 256, 0, stream>>>(mbf, f0, f1, f2, Sall);
  gram_mfma_k<<<dim3(32, 3, 4), 256, 0, stream>>>(mbf, f0, f1, f2, Gpart);
  gred_k<<<768, 256, 0, stream>>>(Gpart, Gm);
  attn_k<<<dim3(4, 4, 3), 256, 0, stream>>>(Gm, Sall, Wq, bq, Wk, bk, attb);

  // ---- collapse attn@v + concat + W_fuse
  m_k<<<dim3(128, 4, 3), 128, 0, stream>>>(W_fu, attb, bv, Mb, cb);
  weff_k<<<dim3(128, 4, 3), 128, 0, stream>>>(Mb, Wv, wefb);
  fuse_mfma_k<<<dim3(128, 2, 4), 256, 0, stream>>>(wefb, f0t, f1t, f2t, b_fu, cb, bufA, s_fuse);

  // ---- att_in = merged + silu(GN(fused_pre)); att_out = GN(att_in) -> NHWC bf16
  gn_silu_add_k<<<4096, 256, 0, stream>>>(bufA, s_fuse, gfug, gfub, bufB, s_gnout);
  gnout_nhwc_k<<<dim3(256, 4, 4), 256, 0, stream>>>(bufA, s_gnout, goug, goub, xbf);

  // ---- r1 = relu(BN(conv(att_out, W_r1)))
  conv4_k<128, 128, 64, 2, 4><<<dim3(128, 4, 2), 256, 0, stream>>>(xbf, wpk_r1, bufB, 128);
  bn_sums_k<<<dim3(128, 16), 256, 0, stream>>>(bufB, s_bn1, 128);
  bnrelu_nhwc_k<<<dim3(256, 4, 4), 256, 0, stream>>>(bufB, s_bn1, bn1g, bn1b, xbf);

  // ---- r2 = relu(BN(conv(r1, W_r2))) -> d_out
  conv4_k<128, 128, 64, 2, 4><<<dim3(128, 4, 2), 256, 0, stream>>>(xbf, wpk_r2, out, 128);
  bn_sums_k<<<dim3(128, 16), 256, 0, stream>>>(out, s_bn2, 128);
  bn_apply8_k<<<4096, 256, 0, stream>>>(out, s_bn2, bn2g, bn2b, nullptr, nullptr);
}